// Round 8
// baseline (374.215 us; speedup 1.0000x reference)
//
#include <hip/hip_runtime.h>

#define FDIM 75
#define CDIM 150          // 2*FDIM
#define NSB 80            // bf16 node row stride (elements) = 160 B
#define BW 7              // bucket width: 128 nodes per bucket
#define BSZ (1 << BW)
#define TILE_E 4096       // edges per partition tile
#define EPT 16            // edges per thread in bpart

typedef __attribute__((ext_vector_type(8))) short bf16x8;
typedef __attribute__((ext_vector_type(4))) float f32x4;
typedef __attribute__((ext_vector_type(4))) int   i32x4;

__device__ __forceinline__ unsigned f2bf(float x) {   // RNE f32->bf16
    unsigned u = __float_as_uint(x);
    return (u + 0x7FFFu + ((u >> 16) & 1u)) >> 16;
}
__device__ __forceinline__ float bf_lo(unsigned u) { return __uint_as_float(u << 16); }
__device__ __forceinline__ float bf_hi(unsigned u) { return __uint_as_float(u & 0xFFFF0000u); }

// ---- convert input h [N,75] f32 -> bf16 [N,80] (pads zero) ----
__global__ void pad_convert_kernel(const float* __restrict__ h_in,
                                   unsigned* __restrict__ h40, int n_nodes) {
    int i = blockIdx.x * blockDim.x + threadIdx.x;   // one dword (2 feats)
    int total = n_nodes * 40;
    if (i >= total) return;
    int v = i / 40, d = i - v * 40;
    int f0 = 2 * d, f1 = 2 * d + 1;
    float a = (f0 < FDIM) ? h_in[(size_t)v * FDIM + f0] : 0.0f;
    float b = (f1 < FDIM) ? h_in[(size_t)v * FDIM + f1] : 0.0f;
    h40[i] = f2bf(a) | (f2bf(b) << 16);
}

// ---- pack U into B-fragment order: wpack[(kb*80+c)*8+j] = W[kb*8+j][c] ----
__global__ void wprep_kernel(const float* __restrict__ Uw,
                             unsigned short* __restrict__ wpack) {
    int i = blockIdx.x * blockDim.x + threadIdx.x;   // 20*80 = 1600 items
    if (i >= 1600) return;
    int kb = i / 80, c = i - kb * 80;
    unsigned short out[8];
#pragma unroll
    for (int j = 0; j < 8; ++j) {
        int k = kb * 8 + j;
        float v = 0.0f;
        if (c < FDIM) {
            if (k < FDIM)                 v = Uw[(size_t)c * CDIM + k];
            else if (k >= 80 && k < 155)  v = Uw[(size_t)c * CDIM + FDIM + (k - 80)];
        }
        out[j] = (unsigned short)f2bf(v);
    }
    *(i32x4*)&wpack[(size_t)i * 8] = *(i32x4*)out;
}

// =================== bucketed CSR build ===================
__global__ __launch_bounds__(256) void bcount_kernel(
        const int* __restrict__ edst, int* __restrict__ bcnt,
        int n_edges, int nb) {
    __shared__ int lh[1024];
    int tid = threadIdx.x;
    for (int i = tid; i < nb; i += 256) lh[i] = 0;
    __syncthreads();
    for (int e = blockIdx.x * blockDim.x + tid; e < n_edges;
         e += gridDim.x * blockDim.x)
        atomicAdd(&lh[edst[e] >> BW], 1);
    __syncthreads();
    for (int i = tid; i < nb; i += 256)
        if (lh[i]) atomicAdd(&bcnt[i], lh[i]);
}

__global__ __launch_bounds__(1024) void bscan_kernel(
        const int* __restrict__ bcnt, int* __restrict__ bbase,
        int* __restrict__ gcur, int* __restrict__ row_ptr,
        int nb, int n_nodes) {
    __shared__ int s[1024];
    int t = threadIdx.x;
    int v = (t < nb) ? bcnt[t] : 0;
    s[t] = v;
    __syncthreads();
    for (int off = 1; off < 1024; off <<= 1) {
        int x = (t >= off) ? s[t - off] : 0;
        __syncthreads();
        s[t] += x;
        __syncthreads();
    }
    if (t < nb) {
        int ex = s[t] - v;
        bbase[t] = ex;
        gcur[t] = ex;
    }
    if (t == nb - 1) {
        bbase[nb] = s[t];
        row_ptr[n_nodes] = s[t];
    }
}

__global__ __launch_bounds__(256) void bpart_kernel(
        const int* __restrict__ esrc, const int* __restrict__ edst,
        int* __restrict__ gcur, unsigned* __restrict__ pairs,
        int n_edges, int nb) {
    __shared__ int lh[1024];
    __shared__ int tbase[1024];
    int tid = threadIdx.x;
    int base = blockIdx.x * TILE_E;
    unsigned packedR[EPT];
    int bR[EPT];
    for (int i = tid; i < nb; i += 256) lh[i] = 0;
    __syncthreads();
#pragma unroll
    for (int k = 0; k < EPT; ++k) {
        int e = base + k * 256 + tid;
        if (e < n_edges) {
            int d = edst[e];
            int s = esrc[e];
            bR[k] = d >> BW;
            packedR[k] = ((unsigned)(d & (BSZ - 1)) << 17) | (unsigned)s;
            atomicAdd(&lh[bR[k]], 1);
        } else {
            bR[k] = -1;
        }
    }
    __syncthreads();
    for (int i = tid; i < nb; i += 256) {
        int c = lh[i];
        if (c) tbase[i] = atomicAdd(&gcur[i], c);
        lh[i] = 0;
    }
    __syncthreads();
#pragma unroll
    for (int k = 0; k < EPT; ++k) {
        if (bR[k] >= 0) {
            int off = atomicAdd(&lh[bR[k]], 1);
            pairs[tbase[bR[k]] + off] = packedR[k];
        }
    }
}

__global__ __launch_bounds__(256) void bfill_kernel(
        const unsigned* __restrict__ pairs, const int* __restrict__ bbase,
        int* __restrict__ row_ptr, int* __restrict__ csr, int n_nodes) {
    __shared__ int cnt[BSZ];
    __shared__ int ofs[BSZ];
    __shared__ int cur[BSZ];
    int b = blockIdx.x;
    int tid = threadIdx.x;
    int v0 = b << BW;
    int nbk = n_nodes - v0;
    if (nbk > BSZ) nbk = BSZ;
    int sbeg = bbase[b];
    int ne = bbase[b + 1] - sbeg;
    if (tid < BSZ) { cnt[tid] = 0; cur[tid] = 0; }
    __syncthreads();
    for (int i = tid; i < ne; i += 256)
        atomicAdd(&cnt[pairs[sbeg + i] >> 17], 1);
    __syncthreads();
    if (tid < BSZ) ofs[tid] = cnt[tid];
    __syncthreads();
    for (int off = 1; off < BSZ; off <<= 1) {
        int x = 0;
        if (tid < BSZ && tid >= off) x = ofs[tid - off];
        __syncthreads();
        if (tid < BSZ) ofs[tid] += x;
        __syncthreads();
    }
    if (tid < nbk) row_ptr[v0 + tid] = sbeg + ofs[tid] - cnt[tid];
    __syncthreads();
    for (int i = tid; i < ne; i += 256) {
        unsigned p = pairs[sbeg + i];
        int dl = p >> 17;
        int src = p & 0x1FFFF;
        int pos = (ofs[dl] - cnt[dl]) + atomicAdd(&cur[dl], 1);
        csr[sbeg + pos] = src;
    }
}

// ======= fused depth: h_out = relu([h_in ; gather(h_in)] @ Wpack + Ub) =======
// Block = 256 threads / 64 nodes. Wave w gathers its 16 nodes into Xl[w]
// (LDS is the transpose between gather's feature-lanes and MFMA's node-rows),
// then runs the 25-MFMA tile with B-fragments streamed from global wpack
// (25.6 KB, L1-resident). Double-buffered h: no cross-block race.
__global__ __launch_bounds__(256) void depth_fused_kernel(
        const unsigned* __restrict__ hin32,      // [N][40] dwords (bf16x2)
        unsigned short* __restrict__ hout,       // [N][80] bf16
        const int* __restrict__ row_ptr, const int* __restrict__ csr,
        const unsigned short* __restrict__ wpack, const float* __restrict__ Ub,
        int n_nodes) {
    __shared__ __align__(16) unsigned short Xl[4][16][168];   // 21.5 KB
    int tid = threadIdx.x;
    int w = tid >> 6, lane = tid & 63;
    int base = blockIdx.x * 64;
    bool act = (lane < 40);    // lane owns feature dwords: h[lane], m[lane]

    // ---- Phase A: gather + stage [h;m] for this wave's 16 nodes ----
    for (int i = 0; i < 16; ++i) {
        int v = base + w * 16 + i;
        if (v < n_nodes) {
            unsigned hv = act ? hin32[(size_t)v * 40 + lane] : 0u;
            int e0 = row_ptr[v], e1 = row_ptr[v + 1];
            float a0 = 0.f, a1 = 0.f, a2 = 0.f, a3 = 0.f;
            float c0 = 0.f, c1 = 0.f, c2 = 0.f, c3 = 0.f;
            int e = e0;
            while (e < e1) {
                int cnt = e1 - e;
                if (cnt > 64) cnt = 64;
                int myi = (lane < cnt) ? csr[e + lane] : 0;
                int d = 0;
                for (; d + 8 <= cnt; d += 8) {
                    int s0 = __shfl(myi, d + 0);
                    int s1 = __shfl(myi, d + 1);
                    int s2 = __shfl(myi, d + 2);
                    int s3 = __shfl(myi, d + 3);
                    int s4 = __shfl(myi, d + 4);
                    int s5 = __shfl(myi, d + 5);
                    int s6 = __shfl(myi, d + 6);
                    int s7 = __shfl(myi, d + 7);
                    if (act) {
                        unsigned u0 = hin32[(size_t)s0 * 40 + lane];
                        unsigned u1 = hin32[(size_t)s1 * 40 + lane];
                        unsigned u2 = hin32[(size_t)s2 * 40 + lane];
                        unsigned u3 = hin32[(size_t)s3 * 40 + lane];
                        unsigned u4 = hin32[(size_t)s4 * 40 + lane];
                        unsigned u5 = hin32[(size_t)s5 * 40 + lane];
                        unsigned u6 = hin32[(size_t)s6 * 40 + lane];
                        unsigned u7 = hin32[(size_t)s7 * 40 + lane];
                        a0 += bf_lo(u0); c0 += bf_hi(u0);
                        a1 += bf_lo(u1); c1 += bf_hi(u1);
                        a2 += bf_lo(u2); c2 += bf_hi(u2);
                        a3 += bf_lo(u3); c3 += bf_hi(u3);
                        a0 += bf_lo(u4); c0 += bf_hi(u4);
                        a1 += bf_lo(u5); c1 += bf_hi(u5);
                        a2 += bf_lo(u6); c2 += bf_hi(u6);
                        a3 += bf_lo(u7); c3 += bf_hi(u7);
                    }
                }
                for (; d + 4 <= cnt; d += 4) {
                    int s0 = __shfl(myi, d + 0);
                    int s1 = __shfl(myi, d + 1);
                    int s2 = __shfl(myi, d + 2);
                    int s3 = __shfl(myi, d + 3);
                    if (act) {
                        unsigned u0 = hin32[(size_t)s0 * 40 + lane];
                        unsigned u1 = hin32[(size_t)s1 * 40 + lane];
                        unsigned u2 = hin32[(size_t)s2 * 40 + lane];
                        unsigned u3 = hin32[(size_t)s3 * 40 + lane];
                        a0 += bf_lo(u0); c0 += bf_hi(u0);
                        a1 += bf_lo(u1); c1 += bf_hi(u1);
                        a2 += bf_lo(u2); c2 += bf_hi(u2);
                        a3 += bf_lo(u3); c3 += bf_hi(u3);
                    }
                }
                for (; d < cnt; ++d) {
                    int s0 = __shfl(myi, d);
                    if (act) {
                        unsigned u0 = hin32[(size_t)s0 * 40 + lane];
                        a0 += bf_lo(u0); c0 += bf_hi(u0);
                    }
                }
                e += cnt;
            }
            if (act) {
                *(unsigned*)&Xl[w][i][2 * lane] = hv;
                float lo = (a0 + a1) + (a2 + a3);
                float hi = (c0 + c1) + (c2 + c3);
                *(unsigned*)&Xl[w][i][80 + 2 * lane] = f2bf(lo) | (f2bf(hi) << 16);
            }
        } else if (act) {
            *(unsigned*)&Xl[w][i][2 * lane] = 0u;
            *(unsigned*)&Xl[w][i][80 + 2 * lane] = 0u;
        }
    }
    __syncthreads();

    // ---- Phase B: 16-node x 80-feat MFMA tile, K=160 ----
    int col = lane & 15;
    int kb = lane >> 4;
    f32x4 acc[5] = {};
#pragma unroll
    for (int t = 0; t < 5; ++t) {
        bf16x8 a = *(bf16x8*)&Xl[w][col][t * 32 + kb * 8];
#pragma unroll
        for (int jt = 0; jt < 5; ++jt) {
            bf16x8 b = *(const bf16x8*)&wpack[((size_t)((t * 4 + kb) * 80 + jt * 16 + col)) * 8];
            acc[jt] = __builtin_amdgcn_mfma_f32_16x16x32_bf16(a, b, acc[jt], 0, 0, 0);
        }
    }

#pragma unroll
    for (int jt = 0; jt < 5; ++jt) {
        int c = jt * 16 + col;
        float bj = (c < FDIM) ? Ub[c] : 0.0f;   // pad cols: acc==0, bias 0 -> store 0
#pragma unroll
        for (int r = 0; r < 4; ++r) {
            int node = base + w * 16 + kb * 4 + r;
            if (node < n_nodes) {
                float vv = fmaxf(acc[jt][r] + bj, 0.0f);
                hout[(size_t)node * NSB + c] = (unsigned short)f2bf(vv);
            }
        }
    }
}

// =================== readout: block per molecule, no atomics =================
__global__ __launch_bounds__(256) void readout_mol_kernel(
        const unsigned* __restrict__ h32, const float* __restrict__ NNw,
        const int* __restrict__ mol_id, const float* __restrict__ NN_b,
        float* __restrict__ out, int n_nodes) {
    int b = blockIdx.x;
    int lo = 0, hi = n_nodes;
    while (lo < hi) {
        int mid = (lo + hi) >> 1;
        if (mol_id[mid] < b) lo = mid + 1; else hi = mid;
    }
    int start = lo;
    hi = n_nodes;
    while (lo < hi) {
        int mid = (lo + hi) >> 1;
        if (mol_id[mid] < b + 1) lo = mid + 1; else hi = mid;
    }
    int end = lo;

    int tid = threadIdx.x;
    int wave = tid >> 6, lane = tid & 63;
    float w0 = 0.f, w1 = 0.f;
    if (lane < 40) {
        w0 = (2 * lane < FDIM) ? NNw[2 * lane] : 0.f;
        w1 = (2 * lane + 1 < FDIM) ? NNw[2 * lane + 1] : 0.f;
    }
    float wsum = 0.f;
    for (int v = start + wave; v < end; v += 4) {
        if (lane < 40) {
            unsigned u = h32[(size_t)v * 40 + lane];
            wsum += bf_lo(u) * w0 + bf_hi(u) * w1;
        }
    }
    wsum += __shfl_down(wsum, 32);
    wsum += __shfl_down(wsum, 16);
    wsum += __shfl_down(wsum, 8);
    wsum += __shfl_down(wsum, 4);
    wsum += __shfl_down(wsum, 2);
    wsum += __shfl_down(wsum, 1);
    __shared__ float part[4];
    if (lane == 0) part[wave] = wsum;
    __syncthreads();
    if (tid == 0) out[b] = NN_b[0] + part[0] + part[1] + part[2] + part[3];
}

extern "C" void kernel_launch(void* const* d_in, const int* in_sizes, int n_in,
                              void* d_out, int out_size, void* d_ws, size_t ws_size,
                              hipStream_t stream) {
    const float* h_src = (const float*)d_in[0];
    const float* U_w   = (const float*)d_in[1];
    const float* U_b   = (const float*)d_in[2];
    const float* NN_w  = (const float*)d_in[3];
    const float* NN_b  = (const float*)d_in[4];
    const int*   esrc  = (const int*)d_in[5];
    const int*   edst  = (const int*)d_in[6];
    const int*   molid = (const int*)d_in[7];

    int n_nodes  = in_sizes[0] / FDIM;   // 100000
    int n_edges  = in_sizes[5];          // 1600000
    int num_mols = out_size;             // 1024
    const int depth = 3;
    int nb = (n_nodes + BSZ - 1) >> BW;  // 782 buckets

    size_t row_bytes = (size_t)n_nodes * NSB * sizeof(unsigned short);  // 16 MB

    size_t off = 0;
    auto alloc = [&](size_t bytes) {
        size_t o = off;
        off += (bytes + 255) & ~(size_t)255;
        return o;
    };
    char* ws = (char*)d_ws;
    size_t o_hA    = alloc(row_bytes);
    size_t o_hB    = alloc(row_bytes);          // aliased as `pairs` pre-depth0
    size_t o_rp    = alloc(((size_t)n_nodes + 1) * sizeof(int));
    size_t o_csr   = alloc((size_t)n_edges * sizeof(int));
    size_t o_wp    = alloc(12800 * sizeof(unsigned short));
    size_t o_bcnt  = alloc((size_t)(nb + 1) * sizeof(int));
    size_t o_bbase = alloc((size_t)(nb + 1) * sizeof(int));
    size_t o_gcur  = alloc((size_t)(nb + 1) * sizeof(int));
    (void)ws_size;

    float* out = (float*)d_out;
    unsigned short* hA = (unsigned short*)(ws + o_hA);
    unsigned short* hB = (unsigned short*)(ws + o_hB);
    unsigned* pairs = (unsigned*)(ws + o_hB);   // alias: dead once bfill done
    int* row_ptr = (int*)(ws + o_rp);
    int* csr     = (int*)(ws + o_csr);
    unsigned short* wpack = (unsigned short*)(ws + o_wp);
    int* bcnt    = (int*)(ws + o_bcnt);
    int* bbase   = (int*)(ws + o_bbase);
    int* gcur    = (int*)(ws + o_gcur);

    pad_convert_kernel<<<(n_nodes * 40 + 255) / 256, 256, 0, stream>>>(
        h_src, (unsigned*)hA, n_nodes);
    wprep_kernel<<<7, 256, 0, stream>>>(U_w, wpack);

    // ---- bucketed CSR build ----
    hipMemsetAsync(bcnt, 0, (size_t)nb * sizeof(int), stream);
    bcount_kernel<<<256, 256, 0, stream>>>(edst, bcnt, n_edges, nb);
    bscan_kernel<<<1, 1024, 0, stream>>>(bcnt, bbase, gcur, row_ptr, nb, n_nodes);
    bpart_kernel<<<(n_edges + TILE_E - 1) / TILE_E, 256, 0, stream>>>(
        esrc, edst, gcur, pairs, n_edges, nb);
    bfill_kernel<<<nb, 256, 0, stream>>>(pairs, bbase, row_ptr, csr, n_nodes);

    int ublocks = (n_nodes + 63) / 64;
    const unsigned short* hin = hA;
    unsigned short* hout = hB;
    for (int d = 0; d < depth; ++d) {
        depth_fused_kernel<<<ublocks, 256, 0, stream>>>(
            (const unsigned*)hin, hout, row_ptr, csr, wpack, U_b, n_nodes);
        const unsigned short* t = hout;
        hout = (unsigned short*)hin;
        hin = t;
    }

    readout_mol_kernel<<<num_mols, 256, 0, stream>>>(
        (const unsigned*)hin, NN_w, molid, NN_b, out, n_nodes);
}

// Round 9
// 288.892 us; speedup vs baseline: 1.2953x; 1.2953x over previous
//
#include <hip/hip_runtime.h>

#define FDIM 75
#define CDIM 150          // 2*FDIM
#define NSB 80            // bf16 node row stride (elements) = 160 B
#define BW 7              // bucket width: 128 nodes per bucket
#define BSZ (1 << BW)
#define TILE_E 4096       // edges per partition tile
#define EPT 16            // edges per thread in bpart

typedef __attribute__((ext_vector_type(8))) short bf16x8;
typedef __attribute__((ext_vector_type(4))) float f32x4;
typedef __attribute__((ext_vector_type(4))) int   i32x4;

__device__ __forceinline__ unsigned f2bf(float x) {   // RNE f32->bf16
    unsigned u = __float_as_uint(x);
    return (u + 0x7FFFu + ((u >> 16) & 1u)) >> 16;
}
__device__ __forceinline__ float bf_lo(unsigned u) { return __uint_as_float(u << 16); }
__device__ __forceinline__ float bf_hi(unsigned u) { return __uint_as_float(u & 0xFFFF0000u); }

// ---- convert input h [N,75] f32 -> bf16 [N,80] (pads zero) ----
__global__ void pad_convert_kernel(const float* __restrict__ h_in,
                                   unsigned* __restrict__ h40, int n_nodes) {
    int i = blockIdx.x * blockDim.x + threadIdx.x;   // one dword (2 feats)
    int total = n_nodes * 40;
    if (i >= total) return;
    int v = i / 40, d = i - v * 40;
    int f0 = 2 * d, f1 = 2 * d + 1;
    float a = (f0 < FDIM) ? h_in[(size_t)v * FDIM + f0] : 0.0f;
    float b = (f1 < FDIM) ? h_in[(size_t)v * FDIM + f1] : 0.0f;
    h40[i] = f2bf(a) | (f2bf(b) << 16);
}

// ---- pack U into B-fragment order: wpack[(kb*80+c)*8+j] = W[kb*8+j][c] ----
__global__ void wprep_kernel(const float* __restrict__ Uw,
                             unsigned short* __restrict__ wpack) {
    int i = blockIdx.x * blockDim.x + threadIdx.x;   // 20*80 = 1600 items
    if (i >= 1600) return;
    int kb = i / 80, c = i - kb * 80;
    unsigned short out[8];
#pragma unroll
    for (int j = 0; j < 8; ++j) {
        int k = kb * 8 + j;
        float v = 0.0f;
        if (c < FDIM) {
            if (k < FDIM)                 v = Uw[(size_t)c * CDIM + k];
            else if (k >= 80 && k < 155)  v = Uw[(size_t)c * CDIM + FDIM + (k - 80)];
        }
        out[j] = (unsigned short)f2bf(v);
    }
    *(i32x4*)&wpack[(size_t)i * 8] = *(i32x4*)out;
}

// =================== bucketed CSR build ===================
__global__ __launch_bounds__(256) void bcount_kernel(
        const int* __restrict__ edst, int* __restrict__ bcnt,
        int n_edges, int nb) {
    __shared__ int lh[1024];
    int tid = threadIdx.x;
    for (int i = tid; i < nb; i += 256) lh[i] = 0;
    __syncthreads();
    for (int e = blockIdx.x * blockDim.x + tid; e < n_edges;
         e += gridDim.x * blockDim.x)
        atomicAdd(&lh[edst[e] >> BW], 1);
    __syncthreads();
    for (int i = tid; i < nb; i += 256)
        if (lh[i]) atomicAdd(&bcnt[i], lh[i]);
}

__global__ __launch_bounds__(1024) void bscan_kernel(
        const int* __restrict__ bcnt, int* __restrict__ bbase,
        int* __restrict__ gcur, int* __restrict__ row_ptr,
        int nb, int n_nodes) {
    __shared__ int s[1024];
    int t = threadIdx.x;
    int v = (t < nb) ? bcnt[t] : 0;
    s[t] = v;
    __syncthreads();
    for (int off = 1; off < 1024; off <<= 1) {
        int x = (t >= off) ? s[t - off] : 0;
        __syncthreads();
        s[t] += x;
        __syncthreads();
    }
    if (t < nb) {
        int ex = s[t] - v;
        bbase[t] = ex;
        gcur[t] = ex;
    }
    if (t == nb - 1) {
        bbase[nb] = s[t];
        row_ptr[n_nodes] = s[t];
    }
}

__global__ __launch_bounds__(256) void bpart_kernel(
        const int* __restrict__ esrc, const int* __restrict__ edst,
        int* __restrict__ gcur, unsigned* __restrict__ pairs,
        int n_edges, int nb) {
    __shared__ int lh[1024];
    __shared__ int tbase[1024];
    int tid = threadIdx.x;
    int base = blockIdx.x * TILE_E;
    unsigned packedR[EPT];
    int bR[EPT];
    for (int i = tid; i < nb; i += 256) lh[i] = 0;
    __syncthreads();
#pragma unroll
    for (int k = 0; k < EPT; ++k) {
        int e = base + k * 256 + tid;
        if (e < n_edges) {
            int d = edst[e];
            int s = esrc[e];
            bR[k] = d >> BW;
            packedR[k] = ((unsigned)(d & (BSZ - 1)) << 17) | (unsigned)s;
            atomicAdd(&lh[bR[k]], 1);
        } else {
            bR[k] = -1;
        }
    }
    __syncthreads();
    for (int i = tid; i < nb; i += 256) {
        int c = lh[i];
        if (c) tbase[i] = atomicAdd(&gcur[i], c);
        lh[i] = 0;
    }
    __syncthreads();
#pragma unroll
    for (int k = 0; k < EPT; ++k) {
        if (bR[k] >= 0) {
            int off = atomicAdd(&lh[bR[k]], 1);
            pairs[tbase[bR[k]] + off] = packedR[k];
        }
    }
}

__global__ __launch_bounds__(256) void bfill_kernel(
        const unsigned* __restrict__ pairs, const int* __restrict__ bbase,
        int* __restrict__ row_ptr, int* __restrict__ csr, int n_nodes) {
    __shared__ int cnt[BSZ];
    __shared__ int ofs[BSZ];
    __shared__ int cur[BSZ];
    int b = blockIdx.x;
    int tid = threadIdx.x;
    int v0 = b << BW;
    int nbk = n_nodes - v0;
    if (nbk > BSZ) nbk = BSZ;
    int sbeg = bbase[b];
    int ne = bbase[b + 1] - sbeg;
    if (tid < BSZ) { cnt[tid] = 0; cur[tid] = 0; }
    __syncthreads();
    for (int i = tid; i < ne; i += 256)
        atomicAdd(&cnt[pairs[sbeg + i] >> 17], 1);
    __syncthreads();
    if (tid < BSZ) ofs[tid] = cnt[tid];
    __syncthreads();
    for (int off = 1; off < BSZ; off <<= 1) {
        int x = 0;
        if (tid < BSZ && tid >= off) x = ofs[tid - off];
        __syncthreads();
        if (tid < BSZ) ofs[tid] += x;
        __syncthreads();
    }
    if (tid < nbk) row_ptr[v0 + tid] = sbeg + ofs[tid] - cnt[tid];
    __syncthreads();
    for (int i = tid; i < ne; i += 256) {
        unsigned p = pairs[sbeg + i];
        int dl = p >> 17;
        int src = p & 0x1FFFF;
        int pos = (ofs[dl] - cnt[dl]) + atomicAdd(&cur[dl], 1);
        csr[sbeg + pos] = src;
    }
}

// =================== gather (bf16, dual-stream): m[v] = sum h[nbr] ==========
// One wave handles TWO nodes (independent streams, 8-deep each -> 16
// outstanding loads/wave). Lanes 0..39 own feature dwords.
#define LOAD8(myi, dd, A0, A1, C0, C1)                                   \
    {                                                                     \
        int s0 = __shfl(myi, dd + 0), s1 = __shfl(myi, dd + 1);           \
        int s2 = __shfl(myi, dd + 2), s3 = __shfl(myi, dd + 3);           \
        int s4 = __shfl(myi, dd + 4), s5 = __shfl(myi, dd + 5);           \
        int s6 = __shfl(myi, dd + 6), s7 = __shfl(myi, dd + 7);           \
        if (act) {                                                        \
            unsigned u0 = h32[(size_t)s0 * 40 + lane];                    \
            unsigned u1 = h32[(size_t)s1 * 40 + lane];                    \
            unsigned u2 = h32[(size_t)s2 * 40 + lane];                    \
            unsigned u3 = h32[(size_t)s3 * 40 + lane];                    \
            unsigned u4 = h32[(size_t)s4 * 40 + lane];                    \
            unsigned u5 = h32[(size_t)s5 * 40 + lane];                    \
            unsigned u6 = h32[(size_t)s6 * 40 + lane];                    \
            unsigned u7 = h32[(size_t)s7 * 40 + lane];                    \
            A0 += bf_lo(u0); C0 += bf_hi(u0);                             \
            A1 += bf_lo(u1); C1 += bf_hi(u1);                             \
            A0 += bf_lo(u2); C0 += bf_hi(u2);                             \
            A1 += bf_lo(u3); C1 += bf_hi(u3);                             \
            A0 += bf_lo(u4); C0 += bf_hi(u4);                             \
            A1 += bf_lo(u5); C1 += bf_hi(u5);                             \
            A0 += bf_lo(u6); C0 += bf_hi(u6);                             \
            A1 += bf_lo(u7); C1 += bf_hi(u7);                             \
        }                                                                 \
    }

__global__ __launch_bounds__(256) void gather_kernel(
        const unsigned* __restrict__ h32, unsigned* __restrict__ m32,
        const int* __restrict__ row_ptr, const int* __restrict__ csr,
        int n_nodes) {
    int lane = threadIdx.x & 63;
    int wid = blockIdx.x * (blockDim.x >> 6) + (threadIdx.x >> 6);
    int nwaves = gridDim.x * (blockDim.x >> 6);
    bool act = (lane < 40);

    for (int v0 = wid * 2; v0 < n_nodes; v0 += nwaves * 2) {
        int vA = v0;
        int vB = v0 + 1;
        bool hasB = (vB < n_nodes);
        int eA = row_ptr[vA], e1A = row_ptr[vA + 1];
        int eB = hasB ? row_ptr[vB] : 0;
        int e1B = hasB ? row_ptr[vB + 1] : 0;
        float aA0 = 0.f, aA1 = 0.f, cA0 = 0.f, cA1 = 0.f;
        float aB0 = 0.f, aB1 = 0.f, cB0 = 0.f, cB1 = 0.f;

        while (eA < e1A || eB < e1B) {
            int cntA = e1A - eA; if (cntA > 64) cntA = 64; if (cntA < 0) cntA = 0;
            int cntB = e1B - eB; if (cntB > 64) cntB = 64; if (cntB < 0) cntB = 0;
            int myiA = (lane < cntA) ? csr[eA + lane] : 0;
            int myiB = (lane < cntB) ? csr[eB + lane] : 0;
            int dA = 0, dB = 0;
            // dual-stream main loop: 16 loads in flight
            while (dA + 8 <= cntA && dB + 8 <= cntB) {
                LOAD8(myiA, dA, aA0, aA1, cA0, cA1);
                LOAD8(myiB, dB, aB0, aB1, cB0, cB1);
                dA += 8; dB += 8;
            }
            while (dA + 8 <= cntA) { LOAD8(myiA, dA, aA0, aA1, cA0, cA1); dA += 8; }
            while (dB + 8 <= cntB) { LOAD8(myiB, dB, aB0, aB1, cB0, cB1); dB += 8; }
            for (; dA + 4 <= cntA; dA += 4) {
                int s0 = __shfl(myiA, dA + 0), s1 = __shfl(myiA, dA + 1);
                int s2 = __shfl(myiA, dA + 2), s3 = __shfl(myiA, dA + 3);
                if (act) {
                    unsigned u0 = h32[(size_t)s0 * 40 + lane];
                    unsigned u1 = h32[(size_t)s1 * 40 + lane];
                    unsigned u2 = h32[(size_t)s2 * 40 + lane];
                    unsigned u3 = h32[(size_t)s3 * 40 + lane];
                    aA0 += bf_lo(u0); cA0 += bf_hi(u0);
                    aA1 += bf_lo(u1); cA1 += bf_hi(u1);
                    aA0 += bf_lo(u2); cA0 += bf_hi(u2);
                    aA1 += bf_lo(u3); cA1 += bf_hi(u3);
                }
            }
            for (; dB + 4 <= cntB; dB += 4) {
                int s0 = __shfl(myiB, dB + 0), s1 = __shfl(myiB, dB + 1);
                int s2 = __shfl(myiB, dB + 2), s3 = __shfl(myiB, dB + 3);
                if (act) {
                    unsigned u0 = h32[(size_t)s0 * 40 + lane];
                    unsigned u1 = h32[(size_t)s1 * 40 + lane];
                    unsigned u2 = h32[(size_t)s2 * 40 + lane];
                    unsigned u3 = h32[(size_t)s3 * 40 + lane];
                    aB0 += bf_lo(u0); cB0 += bf_hi(u0);
                    aB1 += bf_lo(u1); cB1 += bf_hi(u1);
                    aB0 += bf_lo(u2); cB0 += bf_hi(u2);
                    aB1 += bf_lo(u3); cB1 += bf_hi(u3);
                }
            }
            for (; dA < cntA; ++dA) {
                int s0 = __shfl(myiA, dA);
                if (act) {
                    unsigned u0 = h32[(size_t)s0 * 40 + lane];
                    aA0 += bf_lo(u0); cA0 += bf_hi(u0);
                }
            }
            for (; dB < cntB; ++dB) {
                int s0 = __shfl(myiB, dB);
                if (act) {
                    unsigned u0 = h32[(size_t)s0 * 40 + lane];
                    aB0 += bf_lo(u0); cB0 += bf_hi(u0);
                }
            }
            eA += cntA; eB += cntB;
        }
        if (act) {
            float lo = aA0 + aA1, hi = cA0 + cA1;
            m32[(size_t)vA * 40 + lane] = f2bf(lo) | (f2bf(hi) << 16);
            if (hasB) {
                lo = aB0 + aB1; hi = cB0 + cB1;
                m32[(size_t)vB * 40 + lane] = f2bf(lo) | (f2bf(hi) << 16);
            }
        }
    }
}

// =================== update (MFMA): h = relu([h;m] @ Wpack + Ub) =============
// B-fragments stream from global wpack (25.6 KB, L1-resident); only Xl in LDS.
__global__ __launch_bounds__(256) void update_mfma_kernel(
        unsigned short* __restrict__ h, const unsigned short* __restrict__ m,
        const unsigned short* __restrict__ wpack, const float* __restrict__ Ub,
        int n_nodes) {
    __shared__ __align__(16) unsigned short Xl[4][16][168]; // 21.5 KB
    int tid = threadIdx.x;

    int base = blockIdx.x * 64;
    for (int i = tid; i < 64 * 20; i += 256) {
        int nl = i / 20, p = i - nl * 20;
        int v = base + nl;
        i32x4 val = {0, 0, 0, 0};
        if (v < n_nodes) {
            const unsigned short* src = (p < 10)
                ? h + (size_t)v * NSB + p * 8
                : m + (size_t)v * NSB + (p - 10) * 8;
            val = *(const i32x4*)src;
        }
        *(i32x4*)&Xl[nl >> 4][nl & 15][p * 8] = val;
    }
    __syncthreads();

    int w = tid >> 6;
    int lane = tid & 63;
    int col = lane & 15;
    int kb = lane >> 4;

    f32x4 acc[5] = {};
#pragma unroll
    for (int t = 0; t < 5; ++t) {
        bf16x8 a = *(bf16x8*)&Xl[w][col][t * 32 + kb * 8];
#pragma unroll
        for (int jt = 0; jt < 5; ++jt) {
            bf16x8 b = *(const bf16x8*)&wpack[((size_t)((t * 4 + kb) * 80 + jt * 16 + col)) * 8];
            acc[jt] = __builtin_amdgcn_mfma_f32_16x16x32_bf16(a, b, acc[jt], 0, 0, 0);
        }
    }

#pragma unroll
    for (int jt = 0; jt < 5; ++jt) {
        int c = jt * 16 + col;
        float bj = (c < FDIM) ? Ub[c] : 0.0f;   // pad cols: acc==0, bias 0 -> 0
#pragma unroll
        for (int r = 0; r < 4; ++r) {
            int node = base + w * 16 + kb * 4 + r;
            if (node < n_nodes) {
                float vv = fmaxf(acc[jt][r] + bj, 0.0f);
                h[(size_t)node * NSB + c] = (unsigned short)f2bf(vv);
            }
        }
    }
}

// =================== readout: block per molecule, no atomics =================
__global__ __launch_bounds__(256) void readout_mol_kernel(
        const unsigned* __restrict__ h32, const float* __restrict__ NNw,
        const int* __restrict__ mol_id, const float* __restrict__ NN_b,
        float* __restrict__ out, int n_nodes) {
    int b = blockIdx.x;
    int lo = 0, hi = n_nodes;
    while (lo < hi) {
        int mid = (lo + hi) >> 1;
        if (mol_id[mid] < b) lo = mid + 1; else hi = mid;
    }
    int start = lo;
    hi = n_nodes;
    while (lo < hi) {
        int mid = (lo + hi) >> 1;
        if (mol_id[mid] < b + 1) lo = mid + 1; else hi = mid;
    }
    int end = lo;

    int tid = threadIdx.x;
    int wave = tid >> 6, lane = tid & 63;
    float w0 = 0.f, w1 = 0.f;
    if (lane < 40) {
        w0 = (2 * lane < FDIM) ? NNw[2 * lane] : 0.f;
        w1 = (2 * lane + 1 < FDIM) ? NNw[2 * lane + 1] : 0.f;
    }
    float wsum = 0.f;
    for (int v = start + wave; v < end; v += 4) {
        if (lane < 40) {
            unsigned u = h32[(size_t)v * 40 + lane];
            wsum += bf_lo(u) * w0 + bf_hi(u) * w1;
        }
    }
    wsum += __shfl_down(wsum, 32);
    wsum += __shfl_down(wsum, 16);
    wsum += __shfl_down(wsum, 8);
    wsum += __shfl_down(wsum, 4);
    wsum += __shfl_down(wsum, 2);
    wsum += __shfl_down(wsum, 1);
    __shared__ float part[4];
    if (lane == 0) part[wave] = wsum;
    __syncthreads();
    if (tid == 0) out[b] = NN_b[0] + part[0] + part[1] + part[2] + part[3];
}

extern "C" void kernel_launch(void* const* d_in, const int* in_sizes, int n_in,
                              void* d_out, int out_size, void* d_ws, size_t ws_size,
                              hipStream_t stream) {
    const float* h_src = (const float*)d_in[0];
    const float* U_w   = (const float*)d_in[1];
    const float* U_b   = (const float*)d_in[2];
    const float* NN_w  = (const float*)d_in[3];
    const float* NN_b  = (const float*)d_in[4];
    const int*   esrc  = (const int*)d_in[5];
    const int*   edst  = (const int*)d_in[6];
    const int*   molid = (const int*)d_in[7];

    int n_nodes  = in_sizes[0] / FDIM;   // 100000
    int n_edges  = in_sizes[5];          // 1600000
    int num_mols = out_size;             // 1024
    const int depth = 3;
    int nb = (n_nodes + BSZ - 1) >> BW;  // 782 buckets

    size_t row_bytes = (size_t)n_nodes * NSB * sizeof(unsigned short);  // 16 MB

    size_t off = 0;
    auto alloc = [&](size_t bytes) {
        size_t o = off;
        off += (bytes + 255) & ~(size_t)255;
        return o;
    };
    char* ws = (char*)d_ws;
    size_t o_h     = alloc(row_bytes);
    size_t o_m     = alloc(row_bytes);          // aliased as `pairs` pre-gather
    size_t o_rp    = alloc(((size_t)n_nodes + 1) * sizeof(int));
    size_t o_csr   = alloc((size_t)n_edges * sizeof(int));
    size_t o_wp    = alloc(12800 * sizeof(unsigned short));
    size_t o_bcnt  = alloc((size_t)(nb + 1) * sizeof(int));
    size_t o_bbase = alloc((size_t)(nb + 1) * sizeof(int));
    size_t o_gcur  = alloc((size_t)(nb + 1) * sizeof(int));
    (void)ws_size;

    float* out = (float*)d_out;
    unsigned short* h = (unsigned short*)(ws + o_h);
    unsigned short* m = (unsigned short*)(ws + o_m);
    unsigned* pairs = (unsigned*)(ws + o_m);
    int* row_ptr = (int*)(ws + o_rp);
    int* csr     = (int*)(ws + o_csr);
    unsigned short* wpack = (unsigned short*)(ws + o_wp);
    int* bcnt    = (int*)(ws + o_bcnt);
    int* bbase   = (int*)(ws + o_bbase);
    int* gcur    = (int*)(ws + o_gcur);

    pad_convert_kernel<<<(n_nodes * 40 + 255) / 256, 256, 0, stream>>>(
        h_src, (unsigned*)h, n_nodes);
    wprep_kernel<<<7, 256, 0, stream>>>(U_w, wpack);

    // ---- bucketed CSR build ----
    hipMemsetAsync(bcnt, 0, (size_t)nb * sizeof(int), stream);
    bcount_kernel<<<256, 256, 0, stream>>>(edst, bcnt, n_edges, nb);
    bscan_kernel<<<1, 1024, 0, stream>>>(bcnt, bbase, gcur, row_ptr, nb, n_nodes);
    bpart_kernel<<<(n_edges + TILE_E - 1) / TILE_E, 256, 0, stream>>>(
        esrc, edst, gcur, pairs, n_edges, nb);
    bfill_kernel<<<nb, 256, 0, stream>>>(pairs, bbase, row_ptr, csr, n_nodes);

    int ublocks = (n_nodes + 63) / 64;
    for (int d = 0; d < depth; ++d) {
        gather_kernel<<<2048, 256, 0, stream>>>(
            (const unsigned*)h, (unsigned*)m, row_ptr, csr, n_nodes);
        update_mfma_kernel<<<ublocks, 256, 0, stream>>>(h, m, wpack, U_b, n_nodes);
    }

    readout_mol_kernel<<<num_mols, 256, 0, stream>>>(
        (const unsigned*)h, NN_w, molid, NN_b, out, n_nodes);
}

// Round 10
// 259.543 us; speedup vs baseline: 1.4418x; 1.1131x over previous
//
#include <hip/hip_runtime.h>

#define FDIM 75
#define CDIM 150          // 2*FDIM
#define NSB 80            // bf16 node row stride (elements) = 160 B
#define BW 7              // bucket width: 128 nodes per bucket
#define BSZ (1 << BW)
#define TILE_E 4096       // edges per partition tile
#define EPT 16            // edges per thread in bpart

typedef __attribute__((ext_vector_type(8))) short bf16x8;
typedef __attribute__((ext_vector_type(4))) float f32x4;
typedef __attribute__((ext_vector_type(4))) int   i32x4;

__device__ __forceinline__ unsigned f2bf(float x) {   // RNE f32->bf16
    unsigned u = __float_as_uint(x);
    return (u + 0x7FFFu + ((u >> 16) & 1u)) >> 16;
}
__device__ __forceinline__ float bf_lo(unsigned u) { return __uint_as_float(u << 16); }
__device__ __forceinline__ float bf_hi(unsigned u) { return __uint_as_float(u & 0xFFFF0000u); }

// ---- fused pre-pass: pad/convert h, pack U, zero bcnt ----
__global__ void pre_kernel(const float* __restrict__ h_in,
                           unsigned* __restrict__ h40,
                           const float* __restrict__ Uw,
                           unsigned short* __restrict__ wpack,
                           int* __restrict__ bcnt,
                           int n_nodes, int nb) {
    int gid = blockIdx.x * blockDim.x + threadIdx.x;
    int total = n_nodes * 40;
    if (gid < total) {
        int v = gid / 40, d = gid - v * 40;
        int f0 = 2 * d, f1 = 2 * d + 1;
        float a = (f0 < FDIM) ? h_in[(size_t)v * FDIM + f0] : 0.0f;
        float b = (f1 < FDIM) ? h_in[(size_t)v * FDIM + f1] : 0.0f;
        h40[gid] = f2bf(a) | (f2bf(b) << 16);
    }
    if (gid < 1600) {   // wpack[(kb*80+c)*8+j] = W[kb*8+j][c]
        int kb = gid / 80, c = gid - kb * 80;
        unsigned short outw[8];
#pragma unroll
        for (int j = 0; j < 8; ++j) {
            int k = kb * 8 + j;
            float v = 0.0f;
            if (c < FDIM) {
                if (k < FDIM)                 v = Uw[(size_t)c * CDIM + k];
                else if (k >= 80 && k < 155)  v = Uw[(size_t)c * CDIM + FDIM + (k - 80)];
            }
            outw[j] = (unsigned short)f2bf(v);
        }
        *(i32x4*)&wpack[(size_t)gid * 8] = *(i32x4*)outw;
    }
    if (gid >= 2048 && gid < 2048 + nb + 1) bcnt[gid - 2048] = 0;
}

// =================== bucketed CSR build ===================
__global__ __launch_bounds__(256) void bcount_kernel(
        const int* __restrict__ edst, int* __restrict__ bcnt,
        int n_edges, int nb) {
    __shared__ int lh[1024];
    int tid = threadIdx.x;
    for (int i = tid; i < nb; i += 256) lh[i] = 0;
    __syncthreads();
    for (int e = blockIdx.x * blockDim.x + tid; e < n_edges;
         e += gridDim.x * blockDim.x)
        atomicAdd(&lh[edst[e] >> BW], 1);
    __syncthreads();
    for (int i = tid; i < nb; i += 256)
        if (lh[i]) atomicAdd(&bcnt[i], lh[i]);
}

// scan bucket counts -> bases + cursors; also init out[] = NN_b
__global__ __launch_bounds__(1024) void bscan_kernel(
        const int* __restrict__ bcnt, int* __restrict__ bbase,
        int* __restrict__ gcur, int* __restrict__ row_ptr,
        int nb, int n_nodes,
        float* __restrict__ out, const float* __restrict__ NN_b, int num_mols) {
    __shared__ int s[1024];
    int t = threadIdx.x;
    if (t < num_mols) out[t] = NN_b[0];
    int v = (t < nb) ? bcnt[t] : 0;
    s[t] = v;
    __syncthreads();
    for (int off = 1; off < 1024; off <<= 1) {
        int x = (t >= off) ? s[t - off] : 0;
        __syncthreads();
        s[t] += x;
        __syncthreads();
    }
    if (t < nb) {
        int ex = s[t] - v;
        bbase[t] = ex;
        gcur[t] = ex;
    }
    if (t == nb - 1) {
        bbase[nb] = s[t];
        row_ptr[n_nodes] = s[t];
    }
}

__global__ __launch_bounds__(256) void bpart_kernel(
        const int* __restrict__ esrc, const int* __restrict__ edst,
        int* __restrict__ gcur, unsigned* __restrict__ pairs,
        int n_edges, int nb) {
    __shared__ int lh[1024];
    __shared__ int tbase[1024];
    int tid = threadIdx.x;
    int base = blockIdx.x * TILE_E;
    unsigned packedR[EPT];
    int bR[EPT];
    for (int i = tid; i < nb; i += 256) lh[i] = 0;
    __syncthreads();
#pragma unroll
    for (int k = 0; k < EPT; ++k) {
        int e = base + k * 256 + tid;
        if (e < n_edges) {
            int d = edst[e];
            int s = esrc[e];
            bR[k] = d >> BW;
            packedR[k] = ((unsigned)(d & (BSZ - 1)) << 17) | (unsigned)s;
            atomicAdd(&lh[bR[k]], 1);
        } else {
            bR[k] = -1;
        }
    }
    __syncthreads();
    for (int i = tid; i < nb; i += 256) {
        int c = lh[i];
        if (c) tbase[i] = atomicAdd(&gcur[i], c);
        lh[i] = 0;
    }
    __syncthreads();
#pragma unroll
    for (int k = 0; k < EPT; ++k) {
        if (bR[k] >= 0) {
            int off = atomicAdd(&lh[bR[k]], 1);
            pairs[tbase[bR[k]] + off] = packedR[k];
        }
    }
}

__global__ __launch_bounds__(256) void bfill_kernel(
        const unsigned* __restrict__ pairs, const int* __restrict__ bbase,
        int* __restrict__ row_ptr, int* __restrict__ csr, int n_nodes) {
    __shared__ int cnt[BSZ];
    __shared__ int ofs[BSZ];
    __shared__ int cur[BSZ];
    int b = blockIdx.x;
    int tid = threadIdx.x;
    int v0 = b << BW;
    int nbk = n_nodes - v0;
    if (nbk > BSZ) nbk = BSZ;
    int sbeg = bbase[b];
    int ne = bbase[b + 1] - sbeg;
    if (tid < BSZ) { cnt[tid] = 0; cur[tid] = 0; }
    __syncthreads();
    for (int i = tid; i < ne; i += 256)
        atomicAdd(&cnt[pairs[sbeg + i] >> 17], 1);
    __syncthreads();
    if (tid < BSZ) ofs[tid] = cnt[tid];
    __syncthreads();
    for (int off = 1; off < BSZ; off <<= 1) {
        int x = 0;
        if (tid < BSZ && tid >= off) x = ofs[tid - off];
        __syncthreads();
        if (tid < BSZ) ofs[tid] += x;
        __syncthreads();
    }
    if (tid < nbk) row_ptr[v0 + tid] = sbeg + ofs[tid] - cnt[tid];
    __syncthreads();
    for (int i = tid; i < ne; i += 256) {
        unsigned p = pairs[sbeg + i];
        int dl = p >> 17;
        int src = p & 0x1FFFF;
        int pos = (ofs[dl] - cnt[dl]) + atomicAdd(&cur[dl], 1);
        csr[sbeg + pos] = src;
    }
}

// =================== gather (bf16, dual-stream) ===================
#define LOAD8(myi, dd, A0, A1, C0, C1)                                   \
    {                                                                     \
        int s0 = __shfl(myi, dd + 0), s1 = __shfl(myi, dd + 1);           \
        int s2 = __shfl(myi, dd + 2), s3 = __shfl(myi, dd + 3);           \
        int s4 = __shfl(myi, dd + 4), s5 = __shfl(myi, dd + 5);           \
        int s6 = __shfl(myi, dd + 6), s7 = __shfl(myi, dd + 7);           \
        if (act) {                                                        \
            unsigned u0 = h32[(size_t)s0 * 40 + lane];                    \
            unsigned u1 = h32[(size_t)s1 * 40 + lane];                    \
            unsigned u2 = h32[(size_t)s2 * 40 + lane];                    \
            unsigned u3 = h32[(size_t)s3 * 40 + lane];                    \
            unsigned u4 = h32[(size_t)s4 * 40 + lane];                    \
            unsigned u5 = h32[(size_t)s5 * 40 + lane];                    \
            unsigned u6 = h32[(size_t)s6 * 40 + lane];                    \
            unsigned u7 = h32[(size_t)s7 * 40 + lane];                    \
            A0 += bf_lo(u0); C0 += bf_hi(u0);                             \
            A1 += bf_lo(u1); C1 += bf_hi(u1);                             \
            A0 += bf_lo(u2); C0 += bf_hi(u2);                             \
            A1 += bf_lo(u3); C1 += bf_hi(u3);                             \
            A0 += bf_lo(u4); C0 += bf_hi(u4);                             \
            A1 += bf_lo(u5); C1 += bf_hi(u5);                             \
            A0 += bf_lo(u6); C0 += bf_hi(u6);                             \
            A1 += bf_lo(u7); C1 += bf_hi(u7);                             \
        }                                                                 \
    }

__global__ __launch_bounds__(256) void gather_kernel(
        const unsigned* __restrict__ h32, unsigned* __restrict__ m32,
        const int* __restrict__ row_ptr, const int* __restrict__ csr,
        int n_nodes) {
    int lane = threadIdx.x & 63;
    int wid = blockIdx.x * (blockDim.x >> 6) + (threadIdx.x >> 6);
    int nwaves = gridDim.x * (blockDim.x >> 6);
    bool act = (lane < 40);

    for (int v0 = wid * 2; v0 < n_nodes; v0 += nwaves * 2) {
        int vA = v0;
        int vB = v0 + 1;
        bool hasB = (vB < n_nodes);
        int eA = row_ptr[vA], e1A = row_ptr[vA + 1];
        int eB = hasB ? row_ptr[vB] : 0;
        int e1B = hasB ? row_ptr[vB + 1] : 0;
        float aA0 = 0.f, aA1 = 0.f, cA0 = 0.f, cA1 = 0.f;
        float aB0 = 0.f, aB1 = 0.f, cB0 = 0.f, cB1 = 0.f;

        while (eA < e1A || eB < e1B) {
            int cntA = e1A - eA; if (cntA > 64) cntA = 64; if (cntA < 0) cntA = 0;
            int cntB = e1B - eB; if (cntB > 64) cntB = 64; if (cntB < 0) cntB = 0;
            int myiA = (lane < cntA) ? csr[eA + lane] : 0;
            int myiB = (lane < cntB) ? csr[eB + lane] : 0;
            int dA = 0, dB = 0;
            while (dA + 8 <= cntA && dB + 8 <= cntB) {
                LOAD8(myiA, dA, aA0, aA1, cA0, cA1);
                LOAD8(myiB, dB, aB0, aB1, cB0, cB1);
                dA += 8; dB += 8;
            }
            while (dA + 8 <= cntA) { LOAD8(myiA, dA, aA0, aA1, cA0, cA1); dA += 8; }
            while (dB + 8 <= cntB) { LOAD8(myiB, dB, aB0, aB1, cB0, cB1); dB += 8; }
            for (; dA + 4 <= cntA; dA += 4) {
                int s0 = __shfl(myiA, dA + 0), s1 = __shfl(myiA, dA + 1);
                int s2 = __shfl(myiA, dA + 2), s3 = __shfl(myiA, dA + 3);
                if (act) {
                    unsigned u0 = h32[(size_t)s0 * 40 + lane];
                    unsigned u1 = h32[(size_t)s1 * 40 + lane];
                    unsigned u2 = h32[(size_t)s2 * 40 + lane];
                    unsigned u3 = h32[(size_t)s3 * 40 + lane];
                    aA0 += bf_lo(u0); cA0 += bf_hi(u0);
                    aA1 += bf_lo(u1); cA1 += bf_hi(u1);
                    aA0 += bf_lo(u2); cA0 += bf_hi(u2);
                    aA1 += bf_lo(u3); cA1 += bf_hi(u3);
                }
            }
            for (; dB + 4 <= cntB; dB += 4) {
                int s0 = __shfl(myiB, dB + 0), s1 = __shfl(myiB, dB + 1);
                int s2 = __shfl(myiB, dB + 2), s3 = __shfl(myiB, dB + 3);
                if (act) {
                    unsigned u0 = h32[(size_t)s0 * 40 + lane];
                    unsigned u1 = h32[(size_t)s1 * 40 + lane];
                    unsigned u2 = h32[(size_t)s2 * 40 + lane];
                    unsigned u3 = h32[(size_t)s3 * 40 + lane];
                    aB0 += bf_lo(u0); cB0 += bf_hi(u0);
                    aB1 += bf_lo(u1); cB1 += bf_hi(u1);
                    aB0 += bf_lo(u2); cB0 += bf_hi(u2);
                    aB1 += bf_lo(u3); cB1 += bf_hi(u3);
                }
            }
            for (; dA < cntA; ++dA) {
                int s0 = __shfl(myiA, dA);
                if (act) {
                    unsigned u0 = h32[(size_t)s0 * 40 + lane];
                    aA0 += bf_lo(u0); cA0 += bf_hi(u0);
                }
            }
            for (; dB < cntB; ++dB) {
                int s0 = __shfl(myiB, dB);
                if (act) {
                    unsigned u0 = h32[(size_t)s0 * 40 + lane];
                    aB0 += bf_lo(u0); cB0 += bf_hi(u0);
                }
            }
            eA += cntA; eB += cntB;
        }
        if (act) {
            float lo = aA0 + aA1, hi = cA0 + cA1;
            m32[(size_t)vA * 40 + lane] = f2bf(lo) | (f2bf(hi) << 16);
            if (hasB) {
                lo = aB0 + aB1; hi = cB0 + cB1;
                m32[(size_t)vB * 40 + lane] = f2bf(lo) | (f2bf(hi) << 16);
            }
        }
    }
}

// =================== update (MFMA) ===================
// LAST==1: skip h store; fuse readout (bias+relu+dot in registers, 16-lane
// reduce, 64-lane segmented scan over sorted mol_id, ~2 atomics/block).
template <int LAST>
__global__ __launch_bounds__(256) void update_mfma_kernel(
        unsigned short* __restrict__ h, const unsigned short* __restrict__ m,
        const unsigned short* __restrict__ wpack, const float* __restrict__ Ub,
        const float* __restrict__ NNw, const int* __restrict__ mol_id,
        float* __restrict__ out, int n_nodes) {
    __shared__ __align__(16) unsigned short Xl[4][16][168]; // 21.5 KB
    __shared__ float pernode[64];
    int tid = threadIdx.x;

    int base = blockIdx.x * 64;
    for (int i = tid; i < 64 * 20; i += 256) {
        int nl = i / 20, p = i - nl * 20;
        int v = base + nl;
        i32x4 val = {0, 0, 0, 0};
        if (v < n_nodes) {
            const unsigned short* src = (p < 10)
                ? h + (size_t)v * NSB + p * 8
                : m + (size_t)v * NSB + (p - 10) * 8;
            val = *(const i32x4*)src;
        }
        *(i32x4*)&Xl[nl >> 4][nl & 15][p * 8] = val;
    }
    __syncthreads();

    int w = tid >> 6;
    int lane = tid & 63;
    int col = lane & 15;
    int kb = lane >> 4;

    f32x4 acc[5] = {};
#pragma unroll
    for (int t = 0; t < 5; ++t) {
        bf16x8 a = *(bf16x8*)&Xl[w][col][t * 32 + kb * 8];
#pragma unroll
        for (int jt = 0; jt < 5; ++jt) {
            bf16x8 b = *(const bf16x8*)&wpack[((size_t)((t * 4 + kb) * 80 + jt * 16 + col)) * 8];
            acc[jt] = __builtin_amdgcn_mfma_f32_16x16x32_bf16(a, b, acc[jt], 0, 0, 0);
        }
    }

    float bj[5], wj[5];
#pragma unroll
    for (int jt = 0; jt < 5; ++jt) {
        int c = jt * 16 + col;
        bj[jt] = (c < FDIM) ? Ub[c] : 0.0f;
        if (LAST) wj[jt] = (c < FDIM) ? NNw[c] : 0.0f;
    }

    if (!LAST) {
#pragma unroll
        for (int jt = 0; jt < 5; ++jt) {
            int c = jt * 16 + col;
#pragma unroll
            for (int r = 0; r < 4; ++r) {
                int node = base + w * 16 + kb * 4 + r;
                if (node < n_nodes) {
                    float vv = fmaxf(acc[jt][r] + bj[jt], 0.0f);
                    h[(size_t)node * NSB + c] = (unsigned short)f2bf(vv);
                }
            }
        }
    } else {
        // per-node readout partials (4 nodes per thread)
        float pd[4];
#pragma unroll
        for (int r = 0; r < 4; ++r) {
            float s = 0.0f;
#pragma unroll
            for (int jt = 0; jt < 5; ++jt)
                s += fmaxf(acc[jt][r] + bj[jt], 0.0f) * wj[jt];
            pd[r] = s;
        }
        // reduce across the 16 lanes (col) of this (w, kb) group
#pragma unroll
        for (int r = 0; r < 4; ++r) {
            pd[r] += __shfl_xor(pd[r], 1, 16);
            pd[r] += __shfl_xor(pd[r], 2, 16);
            pd[r] += __shfl_xor(pd[r], 4, 16);
            pd[r] += __shfl_xor(pd[r], 8, 16);
        }
        if (col == 0) {
#pragma unroll
            for (int r = 0; r < 4; ++r)
                pernode[w * 16 + kb * 4 + r] = pd[r];
        }
        __syncthreads();
        if (tid < 64) {
            int node = base + tid;
            bool valid = (node < n_nodes);
            float val = valid ? pernode[tid] : 0.0f;
            int mol = valid ? mol_id[node] : 0x7FFFFFFF;
            // inclusive segmented scan over 64 lanes
#pragma unroll
            for (int off = 1; off < 64; off <<= 1) {
                float vo = __shfl_up(val, off);
                int mo = __shfl_up(mol, off);
                if (tid >= off && mo == mol) val += vo;
            }
            int nm = __shfl_down(mol, 1);
            bool tail = (tid == 63) || (nm != mol);
            if (tail && mol != 0x7FFFFFFF)
                unsafeAtomicAdd(&out[mol], val);
        }
    }
}

extern "C" void kernel_launch(void* const* d_in, const int* in_sizes, int n_in,
                              void* d_out, int out_size, void* d_ws, size_t ws_size,
                              hipStream_t stream) {
    const float* h_src = (const float*)d_in[0];
    const float* U_w   = (const float*)d_in[1];
    const float* U_b   = (const float*)d_in[2];
    const float* NN_w  = (const float*)d_in[3];
    const float* NN_b  = (const float*)d_in[4];
    const int*   esrc  = (const int*)d_in[5];
    const int*   edst  = (const int*)d_in[6];
    const int*   molid = (const int*)d_in[7];

    int n_nodes  = in_sizes[0] / FDIM;   // 100000
    int n_edges  = in_sizes[5];          // 1600000
    int num_mols = out_size;             // 1024
    const int depth = 3;
    int nb = (n_nodes + BSZ - 1) >> BW;  // 782 buckets

    size_t row_bytes = (size_t)n_nodes * NSB * sizeof(unsigned short);  // 16 MB

    size_t off = 0;
    auto alloc = [&](size_t bytes) {
        size_t o = off;
        off += (bytes + 255) & ~(size_t)255;
        return o;
    };
    char* ws = (char*)d_ws;
    size_t o_h     = alloc(row_bytes);
    size_t o_m     = alloc(row_bytes);          // aliased as `pairs` pre-gather
    size_t o_rp    = alloc(((size_t)n_nodes + 1) * sizeof(int));
    size_t o_csr   = alloc((size_t)n_edges * sizeof(int));
    size_t o_wp    = alloc(12800 * sizeof(unsigned short));
    size_t o_bcnt  = alloc((size_t)(nb + 1) * sizeof(int));
    size_t o_bbase = alloc((size_t)(nb + 1) * sizeof(int));
    size_t o_gcur  = alloc((size_t)(nb + 1) * sizeof(int));
    (void)ws_size;

    float* out = (float*)d_out;
    unsigned short* h = (unsigned short*)(ws + o_h);
    unsigned short* m = (unsigned short*)(ws + o_m);
    unsigned* pairs = (unsigned*)(ws + o_m);
    int* row_ptr = (int*)(ws + o_rp);
    int* csr     = (int*)(ws + o_csr);
    unsigned short* wpack = (unsigned short*)(ws + o_wp);
    int* bcnt    = (int*)(ws + o_bcnt);
    int* bbase   = (int*)(ws + o_bbase);
    int* gcur    = (int*)(ws + o_gcur);

    // pre: pad/convert h + pack W + zero bcnt (one dispatch)
    pre_kernel<<<(n_nodes * 40 + 255) / 256, 256, 0, stream>>>(
        h_src, (unsigned*)h, U_w, wpack, bcnt, n_nodes, nb);

    // ---- bucketed CSR build (+ out init folded into bscan) ----
    bcount_kernel<<<256, 256, 0, stream>>>(edst, bcnt, n_edges, nb);
    bscan_kernel<<<1, 1024, 0, stream>>>(bcnt, bbase, gcur, row_ptr, nb, n_nodes,
                                         out, NN_b, num_mols);
    bpart_kernel<<<(n_edges + TILE_E - 1) / TILE_E, 256, 0, stream>>>(
        esrc, edst, gcur, pairs, n_edges, nb);
    bfill_kernel<<<nb, 256, 0, stream>>>(pairs, bbase, row_ptr, csr, n_nodes);

    int ublocks = (n_nodes + 63) / 64;
    for (int d = 0; d < depth; ++d) {
        gather_kernel<<<2048, 256, 0, stream>>>(
            (const unsigned*)h, (unsigned*)m, row_ptr, csr, n_nodes);
        if (d < depth - 1) {
            update_mfma_kernel<0><<<ublocks, 256, 0, stream>>>(
                h, m, wpack, U_b, NN_w, molid, out, n_nodes);
        } else {
            update_mfma_kernel<1><<<ublocks, 256, 0, stream>>>(
                h, m, wpack, U_b, NN_w, molid, out, n_nodes);
        }
    }
}